// Round 5
// baseline (892.133 us; speedup 1.0000x reference)
//
#include <hip/hip_runtime.h>
#include <hip/hip_bf16.h>
#include <math.h>

// Problem constants (from reference)
#define NN 100000      // nodes
#define NP 3           // metapaths
#define NE 800000      // edges per path
#define NH 4           // heads
#define ND 32          // dim per head
#define HD 128         // H*D
#define NHID 64        // semantic hidden
#define CAP 48         // per-node in-edge cap (Poisson(8): P(deg>=48) ~ 1e-25)
#define XSTR 49        // padded stride for LDS x table
#define NB 782         // coarse buckets of 128 nodes: ceil(NN/128)
#define BCAP 1408      // bucket capacity: Poisson(1024) + 12 sigma

typedef __attribute__((ext_vector_type(8))) short short8;
typedef __attribute__((ext_vector_type(4))) float f32x4;

__device__ __forceinline__ unsigned short f2bf(float f) {
  union { float f; unsigned int u; } v; v.f = f;
  unsigned int r = v.u + 0x7FFFu + ((v.u >> 16) & 1u);   // round-to-nearest-even
  return (unsigned short)(r >> 16);
}
__device__ __forceinline__ float bf2f(unsigned short u) {
  return __uint_as_float(((unsigned int)u) << 16);
}
__device__ __forceinline__ float tanh_fast(float x) {
  return 1.f - 2.f / (1.f + __expf(2.f * x));   // saturates correctly
}

// ---------------- prep: zero bcnt/s + cast h -> bf16 + transpose/cast W, W1 ----------------
__global__ __launch_bounds__(256) void prep_kernel(
    const float* __restrict__ h, const float* __restrict__ W, const float* __restrict__ W1,
    unsigned short* __restrict__ hb, unsigned short* __restrict__ WT,
    unsigned short* __restrict__ W1T, int* __restrict__ bcnt, float* __restrict__ s) {
  int i = blockIdx.x * blockDim.x + threadIdx.x;
  if (i < NN * 32) {                       // cast h, 4 elems per thread
    float4 v = ((const float4*)h)[i];
    ushort4 o;
    o.x = f2bf(v.x); o.y = f2bf(v.y); o.z = f2bf(v.z); o.w = f2bf(v.w);
    ((ushort4*)hb)[i] = o;
  }
  if (i < NP * 128 * 128) {                // WT[p][n][k] = W[p][k][n]
    int p = i >> 14, r = i & 16383, n = r >> 7, k = r & 127;
    WT[i] = f2bf(W[(size_t)p * 16384 + k * 128 + n]);
  }
  if (i < NHID * 128) {                    // W1T[n][k] = W1[k][n]
    int n = i >> 7, k = i & 127;
    W1T[i] = f2bf(W1[(size_t)k * NHID + n]);
  }
  if (i < NP * NB) bcnt[i] = 0;
  if (i < 4) s[i] = 0.f;
}

// ---------------- MFMA feature GEMM (all paths) + fused el/er ----------------
__global__ __launch_bounds__(256) void gemm_mfma_kernel(
    const unsigned short* __restrict__ hb, const unsigned short* __restrict__ WT_all,
    const float* __restrict__ al_all, const float* __restrict__ ar_all,
    unsigned short* __restrict__ featb_all, float* __restrict__ el_all,
    float* __restrict__ er_all) {
  __shared__ unsigned short Bs[128 * 128];   // 32 KB: whole WT[p]
  const int p = blockIdx.y;
  const unsigned short* WTp = WT_all + (size_t)p * 16384;
#pragma unroll
  for (int it = 0; it < 8; ++it)
    ((float4*)Bs)[it * 256 + threadIdx.x] = ((const float4*)WTp)[it * 256 + threadIdx.x];
  __syncthreads();

  const int wid = threadIdx.x >> 6, lane = threadIdx.x & 63;
  const int c = lane & 15, q = lane >> 4;
  const int tile = blockIdx.x * 4 + wid;       // NN/16 = 6250 exact
  const int tc = tile < 6250 ? tile : 6249;    // clamp loads; stores guarded

  f32x4 acc[8];
#pragma unroll
  for (int t = 0; t < 8; ++t) acc[t] = (f32x4){0.f, 0.f, 0.f, 0.f};

  const unsigned short* arow = hb + (size_t)(tc * 16 + c) * 128 + q * 8;
#pragma unroll
  for (int kc = 0; kc < 4; ++kc) {
    short8 a = *(const short8*)(arow + kc * 32);
#pragma unroll
    for (int t = 0; t < 8; ++t) {
      short8 b = *(const short8*)(Bs + (size_t)(t * 16 + c) * 128 + kc * 32 + q * 8);
      acc[t] = __builtin_amdgcn_mfma_f32_16x16x32_bf16(a, b, acc[t], 0, 0, 0);
    }
  }
  if (tile >= 6250) return;

  unsigned short* featb = featb_all + (size_t)p * NN * 128;
#pragma unroll
  for (int t = 0; t < 8; ++t)
#pragma unroll
    for (int i = 0; i < 4; ++i)
      featb[(size_t)(tc * 16 + q * 4 + i) * 128 + t * 16 + c] = f2bf(acc[t][i]);

  const float* al = al_all + p * 128;
  const float* ar = ar_all + p * 128;
  float alv[8], arv[8];
#pragma unroll
  for (int t = 0; t < 8; ++t) { alv[t] = al[t * 16 + c]; arv[t] = ar[t * 16 + c]; }
  float elp[4][4], erp[4][4];   // [i][hh]
#pragma unroll
  for (int i = 0; i < 4; ++i)
#pragma unroll
    for (int hh = 0; hh < 4; ++hh) {
      elp[i][hh] = acc[2 * hh][i] * alv[2 * hh] + acc[2 * hh + 1][i] * alv[2 * hh + 1];
      erp[i][hh] = acc[2 * hh][i] * arv[2 * hh] + acc[2 * hh + 1][i] * arv[2 * hh + 1];
    }
#pragma unroll
  for (int m = 1; m <= 8; m <<= 1)
#pragma unroll
    for (int i = 0; i < 4; ++i)
#pragma unroll
      for (int hh = 0; hh < 4; ++hh) {
        elp[i][hh] += __shfl_xor(elp[i][hh], m);
        erp[i][hh] += __shfl_xor(erp[i][hh], m);
      }
  if (c == 0) {
    float* el = el_all + (size_t)p * NN * 4;
    float* er = er_all + (size_t)p * NN * 4;
#pragma unroll
    for (int i = 0; i < 4; ++i) {
      int row = tc * 16 + q * 4 + i;
      *(float4*)(el + (size_t)row * 4) = make_float4(elp[i][0], elp[i][1], elp[i][2], elp[i][3]);
      *(float4*)(er + (size_t)row * 4) = make_float4(erp[i][0], erp[i][1], erp[i][2], erp[i][3]);
    }
  }
}

// ---------------- binning pass A: edges -> coarse buckets of 128 dst nodes ----------------
// Packed (dst,src) writes land at adjacent atomic slots -> full-line HBM writes.
__global__ __launch_bounds__(256) void binA_kernel(
    const int* __restrict__ src_all, const int* __restrict__ dst_all,
    int* __restrict__ bcnt, int2* __restrict__ bpair) {
  int e = blockIdx.x * 256 + threadIdx.x;
  if (e >= NE) return;
  const int p = blockIdx.y;
  int d = dst_all[(size_t)p * NE + e];
  int s = src_all[(size_t)p * NE + e];
  int b = d >> 7;
  int pos = atomicAdd(&bcnt[p * NB + b], 1);
  if (pos < BCAP) bpair[((size_t)p * NB + b) * BCAP + pos] = make_int2(d, s);
}

// ---------------- binning pass B: one block per (bucket,path) -> per-node elist + cnt ------
// Block-private 24 KB elist region: scatter stays in one XCD's L2, full-line writeback.
__global__ __launch_bounds__(256) void binB_kernel(
    const int2* __restrict__ bpair, const int* __restrict__ bcnt,
    int* __restrict__ cnt_all, int* __restrict__ elist_all) {
  __shared__ int lcnt[128];
  const int b = blockIdx.x, p = blockIdx.y;
  if (threadIdx.x < 128) lcnt[threadIdx.x] = 0;
  __syncthreads();
  int m = bcnt[p * NB + b]; m = m > BCAP ? BCAP : m;
  const int2* pairs = bpair + ((size_t)p * NB + b) * BCAP;
  for (int i = threadIdx.x; i < m; i += 256) {
    int2 e = pairs[i];
    int pos = atomicAdd(&lcnt[e.x & 127], 1);
    if (pos < CAP) elist_all[((size_t)p * NN + e.x) * CAP + pos] = e.y;
  }
  __syncthreads();
  int node = b * 128 + threadIdx.x;
  if (threadIdx.x < 128 && node < NN) {
    int c = lcnt[threadIdx.x];
    cnt_all[(size_t)p * NN + node] = c > CAP ? CAP : c;
  }
}

// ---------------- gather (all paths): one wave per (node,path) -------------------------
// Deferred normalization: out = (sum_j x_j*feat_j)/(sum_j x_j); x_j = exp(leaky(el+er)).
__global__ __launch_bounds__(256) void gather_kernel(
    const unsigned short* __restrict__ featb_all, const float* __restrict__ el_all,
    const float* __restrict__ er_all, const int* __restrict__ cnt_all,
    const int* __restrict__ elist_all, const float* __restrict__ bias_all,
    unsigned short* __restrict__ zb) {
  __shared__ int   s_src[4][CAP];
  __shared__ float s_x[4][4 * XSTR];
  const int p = blockIdx.y;
  const unsigned short* featb = featb_all + (size_t)p * NN * 128;
  const float* el = el_all + (size_t)p * NN * 4;
  const int* elist = elist_all + (size_t)p * NN * CAP;
  const int wid = threadIdx.x >> 6;
  const int lane = threadIdx.x & 63;
  const int n = blockIdx.x * 4 + wid;        // NN % 4 == 0
  int deg = cnt_all[(size_t)p * NN + n];     // already clamped to CAP by binB
  float4 ern = *(const float4*)(er_all + (size_t)p * NN * 4 + (size_t)n * 4);

  // pass 1: lane j computes x for edge j (deg <= 48); no reduction needed.
  float x0 = 0.f, x1 = 0.f, x2 = 0.f, x3 = 0.f;
  int s = 0;
  if (lane < deg) {
    s = elist[(size_t)n * CAP + lane];
    float4 ev = *(const float4*)(el + (size_t)s * 4);
    float e0 = ev.x + ern.x; e0 = fmaxf(e0, 0.2f * e0); x0 = __expf(e0);
    float e1 = ev.y + ern.y; e1 = fmaxf(e1, 0.2f * e1); x1 = __expf(e1);
    float e2 = ev.z + ern.z; e2 = fmaxf(e2, 0.2f * e2); x2 = __expf(e2);
    float e3 = ev.w + ern.w; e3 = fmaxf(e3, 0.2f * e3); x3 = __expf(e3);
  }
  if (lane < CAP) {
    s_src[wid][lane] = s;                  // 0 for lane >= deg (row 0 load, x=0)
    s_x[wid][0 * XSTR + lane] = x0;
    s_x[wid][1 * XSTR + lane] = x1;
    s_x[wid][2 * XSTR + lane] = x2;
    s_x[wid][3 * XSTR + lane] = x3;
  }
  __syncthreads();

  // pass 2: quarter-wave per edge, 4 edges/iter, 16B/lane feat loads, float2 math (pk-fma).
  const int sub = lane >> 4, c16 = lane & 15;
  const int hh = c16 >> 2;                 // cols c16*8..+7 -> head (c16*8)/32
  const int* srcs = s_src[wid];
  const float* xs = &s_x[wid][hh * XSTR];
  float2 acc2[4];
#pragma unroll
  for (int k = 0; k < 4; ++k) acc2[k] = make_float2(0.f, 0.f);
  float d = 0.f;
  int deg4 = (deg + 3) & ~3;
  for (int i = 0; i < deg4; i += 4) {
    int j = i + sub;
    int sj = srcs[j];
    float xv = xs[j];
    uint4 w = *(const uint4*)(featb + (size_t)sj * 128 + c16 * 8);
    d += xv;
    unsigned int wv[4] = {w.x, w.y, w.z, w.w};
#pragma unroll
    for (int k = 0; k < 4; ++k) {
      float lo = __uint_as_float(wv[k] << 16);
      float hi = __uint_as_float(wv[k] & 0xFFFF0000u);
      acc2[k].x += xv * lo;
      acc2[k].y += xv * hi;
    }
  }
  // reduce over the 4 sub-groups (lane bits 4,5)
  d += __shfl_xor(d, 16); d += __shfl_xor(d, 32);
#pragma unroll
  for (int k = 0; k < 4; ++k) {
    acc2[k].x += __shfl_xor(acc2[k].x, 16); acc2[k].x += __shfl_xor(acc2[k].x, 32);
    acc2[k].y += __shfl_xor(acc2[k].y, 16); acc2[k].y += __shfl_xor(acc2[k].y, 32);
  }
  if (sub == 0) {
    float rd = d > 0.f ? 1.f / d : 0.f;
    const float* bias = bias_all + p * 128 + c16 * 8;
    float4 b0 = *(const float4*)(bias);
    float4 b1 = *(const float4*)(bias + 4);
    short8 o;
    o[0] = f2bf(acc2[0].x * rd + b0.x); o[1] = f2bf(acc2[0].y * rd + b0.y);
    o[2] = f2bf(acc2[1].x * rd + b0.z); o[3] = f2bf(acc2[1].y * rd + b0.w);
    o[4] = f2bf(acc2[2].x * rd + b1.x); o[5] = f2bf(acc2[2].y * rd + b1.y);
    o[6] = f2bf(acc2[3].x * rd + b1.z); o[7] = f2bf(acc2[3].y * rd + b1.w);
    *(short8*)(zb + (size_t)n * (NP * 128) + p * 128 + c16 * 8) = o;
  }
}

// ---------------- MFMA semantic scores, reduced in-kernel to s[3] ----------------
__global__ __launch_bounds__(256) void sem_mfma_kernel(
    const unsigned short* __restrict__ zb, const unsigned short* __restrict__ W1T,
    const float* __restrict__ b1, const float* __restrict__ w2,
    float* __restrict__ s) {
  __shared__ float red3[3];
  if (threadIdx.x < 3) red3[threadIdx.x] = 0.f;
  __syncthreads();
  const int wid = threadIdx.x >> 6, lane = threadIdx.x & 63;
  const int tile = blockIdx.x * 4 + wid;       // (NN*NP)/16 = 18750 exact
  const bool active = tile < 18750;
  const int tc = active ? tile : 18749;
  const int c = lane & 15, q = lane >> 4;
  f32x4 acc[4];
#pragma unroll
  for (int t = 0; t < 4; ++t) acc[t] = (f32x4){0.f, 0.f, 0.f, 0.f};

  const unsigned short* arow = zb + (size_t)(tc * 16 + c) * 128 + q * 8;
  const unsigned short* brow = W1T + (size_t)c * 128 + q * 8;
#pragma unroll
  for (int kc = 0; kc < 4; ++kc) {
    short8 a = *(const short8*)(arow + kc * 32);
#pragma unroll
    for (int t = 0; t < 4; ++t) {
      short8 b = *(const short8*)(brow + (size_t)t * 16 * 128 + kc * 32);
      acc[t] = __builtin_amdgcn_mfma_f32_16x16x32_bf16(a, b, acc[t], 0, 0, 0);
    }
  }
  float part[4] = {0.f, 0.f, 0.f, 0.f};
#pragma unroll
  for (int t = 0; t < 4; ++t) {
    float bb = b1[t * 16 + c], ww = w2[t * 16 + c];
#pragma unroll
    for (int i = 0; i < 4; ++i) part[i] += tanh_fast(acc[t][i] + bb) * ww;
  }
#pragma unroll
  for (int m = 1; m <= 8; m <<= 1)
#pragma unroll
    for (int i = 0; i < 4; ++i) part[i] += __shfl_xor(part[i], m);
  if (active && c == 0) {
#pragma unroll
    for (int i = 0; i < 4; ++i)
      atomicAdd(&red3[(tc * 16 + q * 4 + i) % 3], part[i]);
  }
  __syncthreads();
  if (threadIdx.x < 3) atomicAdd(&s[threadIdx.x], red3[threadIdx.x]);
}

// ---------------- beta = softmax(s / N) ----------------
__global__ void beta_kernel(const float* __restrict__ s, float* __restrict__ beta) {
  if (threadIdx.x == 0 && blockIdx.x == 0) {
    float w0 = s[0] / (float)NN, w1 = s[1] / (float)NN, w2 = s[2] / (float)NN;
    float m = fmaxf(w0, fmaxf(w1, w2));
    float e0 = __expf(w0 - m), e1 = __expf(w1 - m), e2 = __expf(w2 - m);
    float inv = 1.f / (e0 + e1 + e2);
    beta[0] = e0 * inv; beta[1] = e1 * inv; beta[2] = e2 * inv;
  }
}

// ---------------- final combine: out = sum_p beta[p] * z[:,p,:] (bf16 z -> fp32 out) ------
__global__ __launch_bounds__(256) void final_kernel(
    const unsigned short* __restrict__ zb, const float* __restrict__ beta,
    float* __restrict__ out) {
  int i = blockIdx.x * blockDim.x + threadIdx.x;   // NN*16 threads, 8 cols each
  if (i >= NN * 16) return;
  int n = i >> 4, g = i & 15;
  float b0 = beta[0], b1 = beta[1], b2 = beta[2];
  const unsigned short* zr = zb + (size_t)n * (NP * 128) + g * 8;
  ushort4 u0a = *(const ushort4*)(zr);
  ushort4 u0b = *(const ushort4*)(zr + 4);
  ushort4 u1a = *(const ushort4*)(zr + 128);
  ushort4 u1b = *(const ushort4*)(zr + 132);
  ushort4 u2a = *(const ushort4*)(zr + 256);
  ushort4 u2b = *(const ushort4*)(zr + 260);
  float4 oa, ob;
  oa.x = b0 * bf2f(u0a.x) + b1 * bf2f(u1a.x) + b2 * bf2f(u2a.x);
  oa.y = b0 * bf2f(u0a.y) + b1 * bf2f(u1a.y) + b2 * bf2f(u2a.y);
  oa.z = b0 * bf2f(u0a.z) + b1 * bf2f(u1a.z) + b2 * bf2f(u2a.z);
  oa.w = b0 * bf2f(u0a.w) + b1 * bf2f(u1a.w) + b2 * bf2f(u2a.w);
  ob.x = b0 * bf2f(u0b.x) + b1 * bf2f(u1b.x) + b2 * bf2f(u2b.x);
  ob.y = b0 * bf2f(u0b.y) + b1 * bf2f(u1b.y) + b2 * bf2f(u2b.y);
  ob.z = b0 * bf2f(u0b.z) + b1 * bf2f(u1b.z) + b2 * bf2f(u2b.z);
  ob.w = b0 * bf2f(u0b.w) + b1 * bf2f(u1b.w) + b2 * bf2f(u2b.w);
  float* op = out + (size_t)n * 128 + g * 8;
  *(float4*)op = oa;
  *(float4*)(op + 4) = ob;
}

extern "C" void kernel_launch(void* const* d_in, const int* in_sizes, int n_in,
                              void* d_out, int out_size, void* d_ws, size_t ws_size,
                              hipStream_t stream) {
  const float* h    = (const float*)d_in[0];
  const int*   esrc = (const int*)d_in[1];
  const int*   edst = (const int*)d_in[2];
  const float* W    = (const float*)d_in[3];
  const float* al   = (const float*)d_in[4];
  const float* ar   = (const float*)d_in[5];
  const float* bias = (const float*)d_in[6];
  const float* w1   = (const float*)d_in[7];
  const float* b1   = (const float*)d_in[8];
  const float* w2   = (const float*)d_in[9];
  float* out = (float*)d_out;

  // workspace layout (~222 MiB).
  // Aliases: bpair lives inside zb (zb first written by gather, after binB consumed bpair);
  //          hb lives inside elist (hb dead after gemm, elist first written by binB).
  unsigned short* zb    = (unsigned short*)d_ws;       // 38,400,000 bf16 = 76.8 MB
  unsigned short* featb = zb + (size_t)38400000;       // 38,400,000 bf16 (3 paths)
  unsigned short* WT    = featb + (size_t)38400000;    // 49,152 bf16
  unsigned short* W1T   = WT + 49152;                  // 8,192 bf16
  float* el   = (float*)(W1T + 8192);                  // 3*NN*4
  float* er   = el + (size_t)NP * NN * 4;              // 3*NN*4
  float* s    = er + (size_t)NP * NN * 4;              // 16
  float* beta = s + 16;                                // 16
  int*   cnt   = (int*)(beta + 16);                    // NP*NN
  int*   elist = cnt + (size_t)NP * NN;                // NP*NN*CAP = 57.6 MB
  int*   bcnt  = elist + (size_t)NP * NN * CAP;        // NP*NB
  unsigned short* hb = (unsigned short*)elist;         // alias: 25.6 MB inside elist region
  int2* bpair = (int2*)zb;                             // alias: 26.4 MB inside zb region

  prep_kernel<<<(NN * 32 + 255) / 256, 256, 0, stream>>>(h, W, w1, hb, WT, W1T, bcnt, s);

  dim3 gemmGrid(NN / 64 + 1, NP);                      // 1563 x 3 (tiles clamped in-kernel)
  gemm_mfma_kernel<<<gemmGrid, 256, 0, stream>>>(hb, WT, al, ar, featb, el, er);

  dim3 binAGrid((NE + 255) / 256, NP);
  binA_kernel<<<binAGrid, 256, 0, stream>>>(esrc, edst, bcnt, bpair);

  dim3 binBGrid(NB, NP);
  binB_kernel<<<binBGrid, 256, 0, stream>>>(bpair, bcnt, cnt, elist);

  dim3 gatherGrid(NN / 4, NP);
  gather_kernel<<<gatherGrid, 256, 0, stream>>>(featb, el, er, cnt, elist, bias, zb);

  sem_mfma_kernel<<<(18750 + 3) / 4, 256, 0, stream>>>(zb, W1T, b1, w2, s);
  beta_kernel<<<1, 64, 0, stream>>>(s, beta);
  final_kernel<<<(NN * 16 + 255) / 256, 256, 0, stream>>>(zb, beta, out);
}

// Round 6
// 599.109 us; speedup vs baseline: 1.4891x; 1.4891x over previous
//
#include <hip/hip_runtime.h>
#include <hip/hip_bf16.h>
#include <math.h>

// Problem constants (from reference)
#define NN 100000      // nodes
#define NP 3           // metapaths
#define NE 800000      // edges per path
#define NH 4           // heads
#define ND 32          // dim per head
#define HD 128         // H*D
#define NHID 64        // semantic hidden
#define CAP 48         // per-node in-edge cap (Poisson(8): P(deg>=48) ~ 1e-25)
#define XSTR 49        // padded stride for LDS x table
#define NSL 8          // dst slices (one per XCD)
#define SLSZ 12500     // NN / NSL
#define FK 40          // edge chunks per slice (NE % FK == 0)

typedef __attribute__((ext_vector_type(8))) short short8;
typedef __attribute__((ext_vector_type(4))) float f32x4;

__device__ __forceinline__ unsigned short f2bf(float f) {
  union { float f; unsigned int u; } v; v.f = f;
  unsigned int r = v.u + 0x7FFFu + ((v.u >> 16) & 1u);   // round-to-nearest-even
  return (unsigned short)(r >> 16);
}
__device__ __forceinline__ float bf2f(unsigned short u) {
  return __uint_as_float(((unsigned int)u) << 16);
}
__device__ __forceinline__ float tanh_fast(float x) {
  return 1.f - 2.f / (1.f + __expf(2.f * x));   // saturates correctly
}

// ---------------- prep: zero cnt/s + cast h -> bf16 + transpose/cast W, W1 ----------------
__global__ __launch_bounds__(256) void prep_kernel(
    const float* __restrict__ h, const float* __restrict__ W, const float* __restrict__ W1,
    unsigned short* __restrict__ hb, unsigned short* __restrict__ WT,
    unsigned short* __restrict__ W1T, int* __restrict__ cnt, float* __restrict__ s) {
  int i = blockIdx.x * blockDim.x + threadIdx.x;
  if (i < NN * 32) {                       // cast h, 4 elems per thread
    float4 v = ((const float4*)h)[i];
    ushort4 o;
    o.x = f2bf(v.x); o.y = f2bf(v.y); o.z = f2bf(v.z); o.w = f2bf(v.w);
    ((ushort4*)hb)[i] = o;
  }
  if (i < NP * 128 * 128) {                // WT[p][n][k] = W[p][k][n]
    int p = i >> 14, r = i & 16383, n = r >> 7, k = r & 127;
    WT[i] = f2bf(W[(size_t)p * 16384 + k * 128 + n]);
  }
  if (i < NHID * 128) {                    // W1T[n][k] = W1[k][n]
    int n = i >> 7, k = i & 127;
    W1T[i] = f2bf(W1[(size_t)k * NHID + n]);
  }
  if (i < NP * NN) cnt[i] = 0;
  if (i < 4) s[i] = 0.f;
}

// ---------------- MFMA feature GEMM (all paths) + fused el/er ----------------
__global__ __launch_bounds__(256) void gemm_mfma_kernel(
    const unsigned short* __restrict__ hb, const unsigned short* __restrict__ WT_all,
    const float* __restrict__ al_all, const float* __restrict__ ar_all,
    unsigned short* __restrict__ featb_all, float* __restrict__ el_all,
    float* __restrict__ er_all) {
  __shared__ unsigned short Bs[128 * 128];   // 32 KB: whole WT[p]
  const int p = blockIdx.y;
  const unsigned short* WTp = WT_all + (size_t)p * 16384;
#pragma unroll
  for (int it = 0; it < 8; ++it)
    ((float4*)Bs)[it * 256 + threadIdx.x] = ((const float4*)WTp)[it * 256 + threadIdx.x];
  __syncthreads();

  const int wid = threadIdx.x >> 6, lane = threadIdx.x & 63;
  const int c = lane & 15, q = lane >> 4;
  const int tile = blockIdx.x * 4 + wid;       // NN/16 = 6250 exact
  const int tc = tile < 6250 ? tile : 6249;    // clamp loads; stores guarded

  f32x4 acc[8];
#pragma unroll
  for (int t = 0; t < 8; ++t) acc[t] = (f32x4){0.f, 0.f, 0.f, 0.f};

  const unsigned short* arow = hb + (size_t)(tc * 16 + c) * 128 + q * 8;
#pragma unroll
  for (int kc = 0; kc < 4; ++kc) {
    short8 a = *(const short8*)(arow + kc * 32);
#pragma unroll
    for (int t = 0; t < 8; ++t) {
      short8 b = *(const short8*)(Bs + (size_t)(t * 16 + c) * 128 + kc * 32 + q * 8);
      acc[t] = __builtin_amdgcn_mfma_f32_16x16x32_bf16(a, b, acc[t], 0, 0, 0);
    }
  }
  if (tile >= 6250) return;

  unsigned short* featb = featb_all + (size_t)p * NN * 128;
#pragma unroll
  for (int t = 0; t < 8; ++t)
#pragma unroll
    for (int i = 0; i < 4; ++i)
      featb[(size_t)(tc * 16 + q * 4 + i) * 128 + t * 16 + c] = f2bf(acc[t][i]);

  const float* al = al_all + p * 128;
  const float* ar = ar_all + p * 128;
  float alv[8], arv[8];
#pragma unroll
  for (int t = 0; t < 8; ++t) { alv[t] = al[t * 16 + c]; arv[t] = ar[t * 16 + c]; }
  float elp[4][4], erp[4][4];   // [i][hh]
#pragma unroll
  for (int i = 0; i < 4; ++i)
#pragma unroll
    for (int hh = 0; hh < 4; ++hh) {
      elp[i][hh] = acc[2 * hh][i] * alv[2 * hh] + acc[2 * hh + 1][i] * alv[2 * hh + 1];
      erp[i][hh] = acc[2 * hh][i] * arv[2 * hh] + acc[2 * hh + 1][i] * arv[2 * hh + 1];
    }
#pragma unroll
  for (int m = 1; m <= 8; m <<= 1)
#pragma unroll
    for (int i = 0; i < 4; ++i)
#pragma unroll
      for (int hh = 0; hh < 4; ++hh) {
        elp[i][hh] += __shfl_xor(elp[i][hh], m);
        erp[i][hh] += __shfl_xor(erp[i][hh], m);
      }
  if (c == 0) {
    float* el = el_all + (size_t)p * NN * 4;
    float* er = er_all + (size_t)p * NN * 4;
#pragma unroll
    for (int i = 0; i < 4; ++i) {
      int row = tc * 16 + q * 4 + i;
      *(float4*)(el + (size_t)row * 4) = make_float4(elp[i][0], elp[i][1], elp[i][2], elp[i][3]);
      *(float4*)(er + (size_t)row * 4) = make_float4(erp[i][0], erp[i][1], erp[i][2], erp[i][3]);
    }
  }
}

// ---------------- XCD-sliced fill: capped per-dst in-edge lists ----------------
// Slice sl = blockIdx.x % 8 handles dst in [sl*12500, (sl+1)*12500); under round-robin
// block->XCD dispatch all writers of a slice share one XCD's L2 -> no line bouncing.
// Each slice re-reads the edge stream (LLC-absorbed). Perf heuristic only; correct
// regardless of actual block->XCD mapping.
__global__ __launch_bounds__(256) void fill_kernel(
    const int* __restrict__ src_all, const int* __restrict__ dst_all,
    int* __restrict__ cnt_all, int* __restrict__ elist_all) {
  const int p = blockIdx.y;
  const int sl = blockIdx.x & 7;
  const int chunk = blockIdx.x >> 3;           // FK chunks of NE/FK edges
  const int lo = sl * SLSZ, hi = lo + SLSZ;
  const int per = NE / FK;
  const int base = chunk * per;
  const int* srcp = src_all + (size_t)p * NE;
  const int* dstp = dst_all + (size_t)p * NE;
  int* cnt = cnt_all + (size_t)p * NN;
  int* elist = elist_all + (size_t)p * NN * CAP;
  for (int e = base + threadIdx.x; e < base + per; e += 256) {
    int d = dstp[e];
    int s = srcp[e];
    if (d >= lo && d < hi) {
      int pos = atomicAdd(&cnt[d], 1);
      if (pos < CAP) elist[(size_t)d * CAP + pos] = s;
    }
  }
}

// ---------------- gather (all paths): one wave per (node,path) -------------------------
// Deferred normalization: out = (sum_j x_j*feat_j)/(sum_j x_j); x_j = exp(leaky(el+er)).
__global__ __launch_bounds__(256) void gather_kernel(
    const unsigned short* __restrict__ featb_all, const float* __restrict__ el_all,
    const float* __restrict__ er_all, const int* __restrict__ cnt_all,
    const int* __restrict__ elist_all, const float* __restrict__ bias_all,
    unsigned short* __restrict__ zb) {
  __shared__ int   s_src[4][CAP];
  __shared__ float s_x[4][4 * XSTR];
  const int p = blockIdx.y;
  const unsigned short* featb = featb_all + (size_t)p * NN * 128;
  const float* el = el_all + (size_t)p * NN * 4;
  const int* elist = elist_all + (size_t)p * NN * CAP;
  const int wid = threadIdx.x >> 6;
  const int lane = threadIdx.x & 63;
  const int n = blockIdx.x * 4 + wid;        // NN % 4 == 0
  int deg = cnt_all[(size_t)p * NN + n]; deg = deg > CAP ? CAP : deg;
  float4 ern = *(const float4*)(er_all + (size_t)p * NN * 4 + (size_t)n * 4);

  // pass 1: lane j computes x for edge j (deg <= 48); no reduction needed.
  float x0 = 0.f, x1 = 0.f, x2 = 0.f, x3 = 0.f;
  int s = 0;
  if (lane < deg) {
    s = elist[(size_t)n * CAP + lane];
    float4 ev = *(const float4*)(el + (size_t)s * 4);
    float e0 = ev.x + ern.x; e0 = fmaxf(e0, 0.2f * e0); x0 = __expf(e0);
    float e1 = ev.y + ern.y; e1 = fmaxf(e1, 0.2f * e1); x1 = __expf(e1);
    float e2 = ev.z + ern.z; e2 = fmaxf(e2, 0.2f * e2); x2 = __expf(e2);
    float e3 = ev.w + ern.w; e3 = fmaxf(e3, 0.2f * e3); x3 = __expf(e3);
  }
  if (lane < CAP) {
    s_src[wid][lane] = s;                  // 0 for lane >= deg (row 0 load, x=0)
    s_x[wid][0 * XSTR + lane] = x0;
    s_x[wid][1 * XSTR + lane] = x1;
    s_x[wid][2 * XSTR + lane] = x2;
    s_x[wid][3 * XSTR + lane] = x3;
  }
  __syncthreads();

  // pass 2: quarter-wave per edge, 4 edges/iter, 16B/lane feat loads, float2 math (pk-fma).
  const int sub = lane >> 4, c16 = lane & 15;
  const int hh = c16 >> 2;                 // cols c16*8..+7 -> head (c16*8)/32
  const int* srcs = s_src[wid];
  const float* xs = &s_x[wid][hh * XSTR];
  float2 acc2[4];
#pragma unroll
  for (int k = 0; k < 4; ++k) acc2[k] = make_float2(0.f, 0.f);
  float d = 0.f;
  int deg4 = (deg + 3) & ~3;
  for (int i = 0; i < deg4; i += 4) {
    int j = i + sub;
    int sj = srcs[j];
    float xv = xs[j];
    uint4 w = *(const uint4*)(featb + (size_t)sj * 128 + c16 * 8);
    d += xv;
    unsigned int wv[4] = {w.x, w.y, w.z, w.w};
#pragma unroll
    for (int k = 0; k < 4; ++k) {
      float lo = __uint_as_float(wv[k] << 16);
      float hi = __uint_as_float(wv[k] & 0xFFFF0000u);
      acc2[k].x += xv * lo;
      acc2[k].y += xv * hi;
    }
  }
  // reduce over the 4 sub-groups (lane bits 4,5)
  d += __shfl_xor(d, 16); d += __shfl_xor(d, 32);
#pragma unroll
  for (int k = 0; k < 4; ++k) {
    acc2[k].x += __shfl_xor(acc2[k].x, 16); acc2[k].x += __shfl_xor(acc2[k].x, 32);
    acc2[k].y += __shfl_xor(acc2[k].y, 16); acc2[k].y += __shfl_xor(acc2[k].y, 32);
  }
  if (sub == 0) {
    float rd = d > 0.f ? 1.f / d : 0.f;
    const float* bias = bias_all + p * 128 + c16 * 8;
    float4 b0 = *(const float4*)(bias);
    float4 b1 = *(const float4*)(bias + 4);
    short8 o;
    o[0] = f2bf(acc2[0].x * rd + b0.x); o[1] = f2bf(acc2[0].y * rd + b0.y);
    o[2] = f2bf(acc2[1].x * rd + b0.z); o[3] = f2bf(acc2[1].y * rd + b0.w);
    o[4] = f2bf(acc2[2].x * rd + b1.x); o[5] = f2bf(acc2[2].y * rd + b1.y);
    o[6] = f2bf(acc2[3].x * rd + b1.z); o[7] = f2bf(acc2[3].y * rd + b1.w);
    *(short8*)(zb + (size_t)n * (NP * 128) + p * 128 + c16 * 8) = o;
  }
}

// ---------------- MFMA semantic scores, reduced in-kernel to s[3] ----------------
__global__ __launch_bounds__(256) void sem_mfma_kernel(
    const unsigned short* __restrict__ zb, const unsigned short* __restrict__ W1T,
    const float* __restrict__ b1, const float* __restrict__ w2,
    float* __restrict__ s) {
  __shared__ float red3[3];
  if (threadIdx.x < 3) red3[threadIdx.x] = 0.f;
  __syncthreads();
  const int wid = threadIdx.x >> 6, lane = threadIdx.x & 63;
  const int tile = blockIdx.x * 4 + wid;       // (NN*NP)/16 = 18750 exact
  const bool active = tile < 18750;
  const int tc = active ? tile : 18749;
  const int c = lane & 15, q = lane >> 4;
  f32x4 acc[4];
#pragma unroll
  for (int t = 0; t < 4; ++t) acc[t] = (f32x4){0.f, 0.f, 0.f, 0.f};

  const unsigned short* arow = zb + (size_t)(tc * 16 + c) * 128 + q * 8;
  const unsigned short* brow = W1T + (size_t)c * 128 + q * 8;
#pragma unroll
  for (int kc = 0; kc < 4; ++kc) {
    short8 a = *(const short8*)(arow + kc * 32);
#pragma unroll
    for (int t = 0; t < 4; ++t) {
      short8 b = *(const short8*)(brow + (size_t)t * 16 * 128 + kc * 32);
      acc[t] = __builtin_amdgcn_mfma_f32_16x16x32_bf16(a, b, acc[t], 0, 0, 0);
    }
  }
  float part[4] = {0.f, 0.f, 0.f, 0.f};
#pragma unroll
  for (int t = 0; t < 4; ++t) {
    float bb = b1[t * 16 + c], ww = w2[t * 16 + c];
#pragma unroll
    for (int i = 0; i < 4; ++i) part[i] += tanh_fast(acc[t][i] + bb) * ww;
  }
#pragma unroll
  for (int m = 1; m <= 8; m <<= 1)
#pragma unroll
    for (int i = 0; i < 4; ++i) part[i] += __shfl_xor(part[i], m);
  if (active && c == 0) {
#pragma unroll
    for (int i = 0; i < 4; ++i)
      atomicAdd(&red3[(tc * 16 + q * 4 + i) % 3], part[i]);
  }
  __syncthreads();
  if (threadIdx.x < 3) atomicAdd(&s[threadIdx.x], red3[threadIdx.x]);
}

// ---------------- final combine (beta inline): out = sum_p softmax(s/N)[p] * z[:,p,:] -----
__global__ __launch_bounds__(256) void final_kernel(
    const unsigned short* __restrict__ zb, const float* __restrict__ s,
    float* __restrict__ out) {
  int i = blockIdx.x * blockDim.x + threadIdx.x;   // NN*16 threads, 8 cols each
  if (i >= NN * 16) return;
  float w0 = s[0] * (1.f / NN), w1 = s[1] * (1.f / NN), w2 = s[2] * (1.f / NN);
  float m = fmaxf(w0, fmaxf(w1, w2));
  float e0 = __expf(w0 - m), e1 = __expf(w1 - m), e2 = __expf(w2 - m);
  float inv = 1.f / (e0 + e1 + e2);
  float b0 = e0 * inv, b1 = e1 * inv, b2 = e2 * inv;
  int n = i >> 4, g = i & 15;
  const unsigned short* zr = zb + (size_t)n * (NP * 128) + g * 8;
  ushort4 u0a = *(const ushort4*)(zr);
  ushort4 u0b = *(const ushort4*)(zr + 4);
  ushort4 u1a = *(const ushort4*)(zr + 128);
  ushort4 u1b = *(const ushort4*)(zr + 132);
  ushort4 u2a = *(const ushort4*)(zr + 256);
  ushort4 u2b = *(const ushort4*)(zr + 260);
  float4 oa, ob;
  oa.x = b0 * bf2f(u0a.x) + b1 * bf2f(u1a.x) + b2 * bf2f(u2a.x);
  oa.y = b0 * bf2f(u0a.y) + b1 * bf2f(u1a.y) + b2 * bf2f(u2a.y);
  oa.z = b0 * bf2f(u0a.z) + b1 * bf2f(u1a.z) + b2 * bf2f(u2a.z);
  oa.w = b0 * bf2f(u0a.w) + b1 * bf2f(u1a.w) + b2 * bf2f(u2a.w);
  ob.x = b0 * bf2f(u0b.x) + b1 * bf2f(u1b.x) + b2 * bf2f(u2b.x);
  ob.y = b0 * bf2f(u0b.y) + b1 * bf2f(u1b.y) + b2 * bf2f(u2b.y);
  ob.z = b0 * bf2f(u0b.z) + b1 * bf2f(u1b.z) + b2 * bf2f(u2b.z);
  ob.w = b0 * bf2f(u0b.w) + b1 * bf2f(u1b.w) + b2 * bf2f(u2b.w);
  float* op = out + (size_t)n * 128 + g * 8;
  *(float4*)op = oa;
  *(float4*)(op + 4) = ob;
}

extern "C" void kernel_launch(void* const* d_in, const int* in_sizes, int n_in,
                              void* d_out, int out_size, void* d_ws, size_t ws_size,
                              hipStream_t stream) {
  const float* h    = (const float*)d_in[0];
  const int*   esrc = (const int*)d_in[1];
  const int*   edst = (const int*)d_in[2];
  const float* W    = (const float*)d_in[3];
  const float* al   = (const float*)d_in[4];
  const float* ar   = (const float*)d_in[5];
  const float* bias = (const float*)d_in[6];
  const float* w1   = (const float*)d_in[7];
  const float* b1   = (const float*)d_in[8];
  const float* w2   = (const float*)d_in[9];
  float* out = (float*)d_out;

  // workspace layout (~216 MiB); hb aliases elist (hb dead after gemm, elist written after)
  unsigned short* zb    = (unsigned short*)d_ws;       // 38,400,000 bf16
  unsigned short* featb = zb + (size_t)38400000;       // 38,400,000 bf16 (3 paths)
  unsigned short* WT    = featb + (size_t)38400000;    // 49,152 bf16
  unsigned short* W1T   = WT + 49152;                  // 8,192 bf16
  float* el   = (float*)(W1T + 8192);                  // 3*NN*4
  float* er   = el + (size_t)NP * NN * 4;              // 3*NN*4
  float* s    = er + (size_t)NP * NN * 4;              // 16
  int*   cnt   = (int*)(s + 16);                       // NP*NN
  int*   elist = cnt + (size_t)NP * NN;                // NP*NN*CAP = 57.6 MB
  unsigned short* hb = (unsigned short*)elist;         // alias: 25.6 MB inside elist region

  prep_kernel<<<(NN * 32 + 255) / 256, 256, 0, stream>>>(h, W, w1, hb, WT, W1T, cnt, s);

  dim3 gemmGrid(NN / 64 + 1, NP);                      // 1563 x 3 (tiles clamped in-kernel)
  gemm_mfma_kernel<<<gemmGrid, 256, 0, stream>>>(hb, WT, al, ar, featb, el, er);

  dim3 fillGrid(NSL * FK, NP);                         // 320 x 3
  fill_kernel<<<fillGrid, 256, 0, stream>>>(esrc, edst, cnt, elist);

  dim3 gatherGrid(NN / 4, NP);
  gather_kernel<<<gatherGrid, 256, 0, stream>>>(featb, el, er, cnt, elist, bias, zb);

  sem_mfma_kernel<<<(18750 + 3) / 4, 256, 0, stream>>>(zb, W1T, b1, w2, s);
  final_kernel<<<(NN * 16 + 255) / 256, 256, 0, stream>>>(zb, s, out);
}